// Round 11
// baseline (589.959 us; speedup 1.0000x reference)
//
#include <hip/hip_runtime.h>
#include <hip/hip_bf16.h>

// STCN read_memory: affinity softmax over THW + value readout.
#define CKDIM 64
#define THW   12960     // 8*30*54
#define THWP  13056     // K padded to 204*64 (zero pad) for the 8-phase GEMM
#define NKT   204       // THWP/64
#define KTCH  51        // K-tiles per ks chunk (4 chunks)
#define HWDIM 1620      // 30*54
#define NOBJ  8
#define CVAL  512
#define NB    4
#define NSTEP 405       // THW / 32
#define NJT   13        // ceil(1620/128)
#define NCHS  8         // stats K-chunks
#define NCHP  4         // fallback fused-PV K-chunks
#define PCH   16        // P-write K-chunks
#define S2F   0.3606737602222409f   // 0.25 * log2(e)

#if defined(__has_builtin)
#if __has_builtin(__builtin_amdgcn_global_load_lds)
#define HAVE_GLL 1
#endif
#endif

using bf16x8 = __attribute__((ext_vector_type(8))) short;
using f32x4  = __attribute__((ext_vector_type(4))) float;

__device__ __forceinline__ unsigned cvtpk(float lo, float hi) {
    unsigned r;
    asm("v_cvt_pk_bf16_f32 %0, %1, %2" : "=v"(r) : "v"(lo), "v"(hi));
    return r;
}
__device__ __forceinline__ unsigned short bf_rne(float x) {
    unsigned u = __float_as_uint(x);
    u += 0x7FFFu + ((u >> 16) & 1u);
    return (unsigned short)(u >> 16);
}
__device__ __forceinline__ float fexp2(float x) {
#if __has_builtin(__builtin_amdgcn_exp2f)
    return __builtin_amdgcn_exp2f(x);
#else
    return __expf(x * 0.69314718055994531f);
#endif
}
#ifdef HAVE_GLL
__device__ __forceinline__ void gload16(const void* g, void* l) {
    __builtin_amdgcn_global_load_lds(
        (const __attribute__((address_space(1))) unsigned int*)g,
        (__attribute__((address_space(3))) unsigned int*)l, 16, 0, 0);
}
#endif

// k8l[b][t] = (sum_c k^2)/8 * log2(e)  (fallback path only)
__global__ void stcn_ksq_kernel(const float* __restrict__ mk, float* __restrict__ k8l) {
    int t = blockIdx.x * 256 + threadIdx.x;
    if (t >= THW) return;
    int b = blockIdx.y;
    const float* p = mk + (size_t)b * CKDIM * THW + t;
    float s = 0.f;
#pragma unroll
    for (int c = 0; c < CKDIM; ++c) { float v = p[(size_t)c * THW]; s = fmaf(v, v, s); }
    k8l[b * THW + t] = s * (0.125f * 1.44269504088896341f);
}

// K [b][c][t] f32 -> kbt [b][t][c] bf16 (RNE), fused k8l
__global__ __launch_bounds__(512)
void stcn_ktr_kernel(const float* __restrict__ mk, unsigned short* __restrict__ kbt,
                     float* __restrict__ k8l) {
    __shared__ unsigned short L[64][72];
    __shared__ float S[64][8];
    const int tid = threadIdx.x, b = blockIdx.y, t0 = blockIdx.x * 64;
    const int tt = tid & 63;
    float a2 = 0.f;
#pragma unroll
    for (int it = 0; it < 8; ++it) {
        int idx = tid + 512 * it;
        int c = idx >> 6;
        int t = t0 + tt;
        float v = (t < THW) ? mk[((size_t)b * CKDIM + c) * THW + t] : 0.f;
        L[tt][c] = bf_rne(v);
        a2 = fmaf(v, v, a2);
    }
    S[tt][tid >> 6] = a2;
    __syncthreads();
    if (tid < 64) {
        float s = 0.f;
#pragma unroll
        for (int q = 0; q < 8; ++q) s += S[tid][q];
        int t = t0 + tid;
        if (t < THW) k8l[b * THW + t] = s * (0.125f * 1.44269504088896341f);
    }
    {
        int tr = tid >> 3, cq = tid & 7;
        int t = t0 + tr;
        if (t < THW) {
            uint4 o = *(const uint4*)&L[tr][8 * cq];
            *(uint4*)(kbt + ((size_t)b * THW + t) * CKDIM + 8 * cq) = o;
        }
    }
}

// V f32 -> bf16 (RNE), into padded rows [row][THWP]
__global__ void stcn_vcvt_kernel(const float* __restrict__ mv, unsigned short* __restrict__ mvb) {
    size_t i = ((size_t)blockIdx.x * 256 + threadIdx.x) * 8;
    if (i >= (size_t)NOBJ * CVAL * THW) return;
    size_t row = i / THW, t = i % THW;     // THW % 8 == 0 -> chunk stays in one row
    float4 v0 = *(const float4*)(mv + i);
    float4 v1 = *(const float4*)(mv + i + 4);
    uint4 o;
    o.x = cvtpk(v0.x, v0.y); o.y = cvtpk(v0.z, v0.w);
    o.z = cvtpk(v1.x, v1.y); o.w = cvtpk(v1.z, v1.w);
    *(uint4*)(mvb + row * THWP + t) = o;
}

// zero the K-pad region of mvb rows and nPr Pws rows
__global__ void stcn_pad0_kernel(unsigned short* __restrict__ mvb,
                                 unsigned short* __restrict__ Pws, int nPr) {
    int idx = blockIdx.x * 256 + threadIdx.x;     // (4096+nPr) rows x 12 chunks of 8
    int rowtot = NOBJ * CVAL + nPr;
    if (idx >= rowtot * 12) return;
    int row = idx / 12, ch = idx % 12;
    unsigned short* base = (row < NOBJ * CVAL)
        ? mvb + (size_t)row * THWP
        : Pws + (size_t)(row - NOBJ * CVAL) * THWP;
    *(uint4*)(base + THW + ch * 8) = make_uint4(0, 0, 0, 0);
}

// ---------------- stats (MODE 0) + fused fallback PV (MODE 1) ----------------
template <int MODE, bool VB16, bool KB16>
__global__ __launch_bounds__(512, (MODE == 1) ? 4 : 1)
void stcn_aff_kernel(const float* __restrict__ mk, const unsigned short* __restrict__ kbt,
                     const float* __restrict__ qk, const float* __restrict__ k8l,
                     float* __restrict__ mpart, float* __restrict__ lpart,
                     const float* __restrict__ mv, const unsigned short* __restrict__ mvb,
                     const int* __restrict__ bmap, float* __restrict__ out)
{
    constexpr int SMEM_BYTES = (MODE == 0) ? 36864 : 45312;
    __shared__ __align__(16) unsigned char smem[SMEM_BYTES];
    unsigned short* KtP   = (unsigned short*)smem;
    float*          k8tP  = (float*)(smem + 9216);
    unsigned short* PtP   = (unsigned short*)(smem + 9472);
    unsigned short* VtP   = (unsigned short*)(smem + 23808);
    float*          mjsP  = (float*)(smem + 44288);
    float*          iljsP = (float*)(smem + 44800);
    unsigned short* QtP   = (unsigned short*)smem;

    const int tid  = threadIdx.x;
    const int w    = tid >> 6;
    const int lane = tid & 63;
    const int g    = lane >> 4;
    const int lr   = lane & 15;

    int b, n = 0, jt, kc, cb = 0;
    if (MODE == 0) { b = blockIdx.y; jt = blockIdx.x >> 3; kc = blockIdx.x & 7; }
    else {
        n = blockIdx.y; jt = blockIdx.x >> 3; kc = (blockIdx.x >> 1) & 3; cb = blockIdx.x & 1;
        b = bmap[n];
    }
    const int jbase = jt * 128;
    const int cbase = cb * 256;

#pragma unroll
    for (int it = 0; it < 8; ++it) {
        int idx = tid + 512 * it;
        int j = idx & 127, cp = idx >> 7;
        int jg = jbase + j;
        float q0 = 0.f, q1 = 0.f;
        if (jg < HWDIM) {
            const float* qp = qk + ((size_t)b * CKDIM + 2 * cp) * HWDIM + jg;
            q0 = qp[0]; q1 = qp[HWDIM];
        }
        unsigned wh = cvtpk(q0, q1);
        float r0 = q0 - __uint_as_float(wh << 16);
        float r1 = q1 - __uint_as_float(wh & 0xFFFF0000u);
        *(unsigned*)&QtP[(0 * 128 + j) * 72 + 2 * cp] = wh;
        *(unsigned*)&QtP[(1 * 128 + j) * 72 + 2 * cp] = cvtpk(r0, r1);
    }
    __syncthreads();
    bf16x8 bqh[2], bql[2];
#pragma unroll
    for (int s = 0; s < 2; ++s) {
        bqh[s] = *(const bf16x8*)&QtP[(0 * 128 + w * 16 + lr) * 72 + 32 * s + 8 * g];
        bql[s] = *(const bf16x8*)&QtP[(1 * 128 + w * 16 + lr) * 72 + 32 * s + 8 * g];
    }
    __syncthreads();

    auto stageK_loads = [&](int st, uint2& k16, float2* kvf) {
        if constexpr (KB16) {
            int tt = tid >> 4, cq = tid & 15;
            k16 = *(const uint2*)(kbt + ((size_t)b * THW + st * 32 + tt) * CKDIM + 4 * cq);
        } else {
#pragma unroll
            for (int it = 0; it < 2; ++it) {
                int idx = tid + 512 * it;
                int tt = idx & 31, cp = idx >> 5;
                const float* kp = mk + ((size_t)b * CKDIM + 2 * cp) * THW + st * 32 + tt;
                kvf[it].x = kp[0];
                kvf[it].y = kp[THW];
            }
        }
    };
    auto stageK_write = [&](int buf, uint2 k16, const float2* kvf) {
        if constexpr (KB16) {
            int tt = tid >> 4, cq = tid & 15;
            *(uint2*)&KtP[(buf * 32 + tt) * 72 + 4 * cq] = k16;
        } else {
#pragma unroll
            for (int it = 0; it < 2; ++it) {
                int idx = tid + 512 * it;
                int tt = idx & 31, cp = idx >> 5;
                *(unsigned*)&KtP[(buf * 32 + tt) * 72 + 2 * cp] = cvtpk(kvf[it].x, kvf[it].y);
            }
        }
    };

    int s0, s1;
    if (MODE == 0) { s0 = (NSTEP * kc) / NCHS; s1 = (NSTEP * (kc + 1)) / NCHS; }
    else           { s0 = (NSTEP * kc) / NCHP; s1 = (NSTEP * (kc + 1)) / NCHP; }

    if (MODE == 1 && tid < 128) {
        int jg = jbase + tid;
        float m = 0.f, l = 0.f;
        if (jg < HWDIM) {
            m = -1e30f;
#pragma unroll
            for (int c = 0; c < NCHS; ++c) {
                float mc = mpart[(b * NCHS + c) * HWDIM + jg];
                float lc = lpart[(b * NCHS + c) * HWDIM + jg];
                float mn = fmaxf(m, mc);
                l = l * fexp2(m - mn) + lc * fexp2(mc - mn);
                m = mn;
            }
        }
        mjsP[tid]  = m;
        iljsP[tid] = (l > 0.f) ? 1.f / l : 0.f;
    }
    {
        uint2 k16; float2 kvf[2];
        stageK_loads(s0, k16, kvf);
        stageK_write(0, k16, kvf);
        if (tid < 32) k8tP[tid] = k8l[b * THW + s0 * 32 + tid];
    }
    __syncthreads();

    float mv_j = 0.f, il_j = 0.f;
    if (MODE == 1) { mv_j = mjsP[w * 16 + lr]; il_j = iljsP[w * 16 + lr]; }

    float m_run = -1e30f, l_run = 0.f;
    f32x4 zz = {0.f, 0.f, 0.f, 0.f};
    f32x4 acc[4][4];
    if (MODE == 1)
#pragma unroll
        for (int i = 0; i < 4; ++i)
#pragma unroll
            for (int j = 0; j < 4; ++j) acc[i][j] = zz;

    const int wc = w >> 1, wj = w & 1;
    const int vc = tid >> 1, vth = tid & 1;

    int cur = 0;
    for (int st = s0; st < s1; ++st) {
        const int t0 = st * 32;
        const bool nxt = (st + 1 < s1);

        uint4 vw0 = {0,0,0,0}, vw1 = {0,0,0,0};
        if (MODE == 1) {
            if (VB16) {
                const unsigned short* vp = mvb + ((size_t)n * CVAL + cbase + vc) * THWP + t0 + vth * 16;
                vw0 = *(const uint4*)vp;
                vw1 = *(const uint4*)(vp + 8);
            } else {
                const float* vp = mv + ((size_t)n * CVAL + cbase + vc) * THW + t0 + vth * 16;
                float4 f0 = *(const float4*)vp;
                float4 f1 = *(const float4*)(vp + 4);
                float4 f2 = *(const float4*)(vp + 8);
                float4 f3 = *(const float4*)(vp + 12);
                vw0 = make_uint4(cvtpk(f0.x,f0.y), cvtpk(f0.z,f0.w), cvtpk(f1.x,f1.y), cvtpk(f1.z,f1.w));
                vw1 = make_uint4(cvtpk(f2.x,f2.y), cvtpk(f2.z,f2.w), cvtpk(f3.x,f3.y), cvtpk(f3.z,f3.w));
            }
        }
        uint2 k16; float2 kvf[2];
        float k8next = 0.f;
        if (nxt) {
            stageK_loads(st + 1, k16, kvf);
            if (tid < 32) k8next = k8l[b * THW + (st + 1) * 32 + tid];
        }
        bf16x8 ak0[2], ak1[2];
#pragma unroll
        for (int s = 0; s < 2; ++s) {
            ak0[s] = *(const bf16x8*)&KtP[(cur * 32 + lr) * 72 + 32 * s + 8 * g];
            ak1[s] = *(const bf16x8*)&KtP[(cur * 32 + 16 + lr) * 72 + 32 * s + 8 * g];
        }
        f32x4 k80 = *(const f32x4*)&k8tP[cur * 32 + 4 * g];
        f32x4 k81 = *(const f32x4*)&k8tP[cur * 32 + 16 + 4 * g];
        f32x4 ab0 = zz, ab1 = zz;
#pragma unroll
        for (int s = 0; s < 2; ++s) {
            ab0 = __builtin_amdgcn_mfma_f32_16x16x32_bf16(ak0[s], bqh[s], ab0, 0, 0, 0);
            ab0 = __builtin_amdgcn_mfma_f32_16x16x32_bf16(ak0[s], bql[s], ab0, 0, 0, 0);
            ab1 = __builtin_amdgcn_mfma_f32_16x16x32_bf16(ak1[s], bqh[s], ab1, 0, 0, 0);
            ab1 = __builtin_amdgcn_mfma_f32_16x16x32_bf16(ak1[s], bql[s], ab1, 0, 0, 0);
        }
        if (nxt) {
            stageK_write(cur ^ 1, k16, kvf);
            if (tid < 32) k8tP[(cur ^ 1) * 32 + tid] = k8next;
        }

        if (MODE == 0) {
            float L0[4], L1[4], tmax = -1e30f;
#pragma unroll
            for (int r = 0; r < 4; ++r) {
                L0[r] = fmaf(ab0[r], S2F, -k80[r]); tmax = fmaxf(tmax, L0[r]);
                L1[r] = fmaf(ab1[r], S2F, -k81[r]); tmax = fmaxf(tmax, L1[r]);
            }
            float ps = 0.f;
#pragma unroll
            for (int r = 0; r < 4; ++r)
                ps += fexp2(L0[r] - tmax) + fexp2(L1[r] - tmax);
            float mn = fmaxf(m_run, tmax);
            l_run = l_run * fexp2(m_run - mn) + ps * fexp2(tmax - mn);
            m_run = mn;
            __syncthreads();
        } else {
            float p0[4], p1[4];
#pragma unroll
            for (int r = 0; r < 4; ++r) {
                p0[r] = fexp2(fmaf(ab0[r], S2F, -k80[r]) - mv_j) * il_j;
                p1[r] = fexp2(fmaf(ab1[r], S2F, -k81[r]) - mv_j) * il_j;
            }
            __syncthreads();
            {
                int jl = w * 16 + lr;
                *(uint2*)&PtP[jl * 56 + 4 * g]      = make_uint2(cvtpk(p0[0], p0[1]), cvtpk(p0[2], p0[3]));
                *(uint2*)&PtP[jl * 56 + 16 + 4 * g] = make_uint2(cvtpk(p1[0], p1[1]), cvtpk(p1[2], p1[3]));
                *(uint4*)&VtP[vc * 40 + vth * 16]     = vw0;
                *(uint4*)&VtP[vc * 40 + vth * 16 + 8] = vw1;
            }
            __syncthreads();
            bf16x8 bp[4];
#pragma unroll
            for (int jf = 0; jf < 4; ++jf)
                bp[jf] = *(const bf16x8*)&PtP[(wj * 64 + jf * 16 + lr) * 56 + 8 * g];
#pragma unroll
            for (int cf = 0; cf < 4; ++cf) {
                bf16x8 av = *(const bf16x8*)&VtP[(wc * 64 + cf * 16 + lr) * 40 + 8 * g];
#pragma unroll
                for (int jf = 0; jf < 4; ++jf)
                    acc[cf][jf] = __builtin_amdgcn_mfma_f32_16x16x32_bf16(av, bp[jf], acc[cf][jf], 0, 0, 0);
            }
        }
        cur ^= 1;
    }

    if (MODE == 0) {
#pragma unroll
        for (int off = 16; off < 64; off <<= 1) {
            float mo = __shfl_xor(m_run, off, 64);
            float lo = __shfl_xor(l_run, off, 64);
            float mn = fmaxf(m_run, mo);
            l_run = l_run * fexp2(m_run - mn) + lo * fexp2(mo - mn);
            m_run = mn;
        }
        int jg = jbase + w * 16 + lr;
        if (g == 0 && jg < HWDIM) {
            mpart[(b * NCHS + kc) * HWDIM + jg] = m_run;
            lpart[(b * NCHS + kc) * HWDIM + jg] = l_run;
        }
    } else {
#pragma unroll
        for (int cf = 0; cf < 4; ++cf) {
#pragma unroll
            for (int jf = 0; jf < 4; ++jf) {
                int jg = jbase + wj * 64 + jf * 16 + lr;
                if (jg < HWDIM) {
                    int c = cbase + wc * 64 + cf * 16 + 4 * g;
                    float* op = out + ((size_t)n * CVAL + c) * HWDIM + jg;
#pragma unroll
                    for (int r = 0; r < 4; ++r)
                        atomicAdd(op + (size_t)r * HWDIM, acc[cf][jf][r]);
                }
            }
        }
    }
}

// ---------------- P-write: softmax'd P (bf16) -> Pws[slot][j][THWP] ----------------
__global__ __launch_bounds__(512)
void stcn_pwrite_kernel(const unsigned short* __restrict__ kbt,
                        const float* __restrict__ qk, const float* __restrict__ k8l,
                        const float* __restrict__ mpart, const float* __restrict__ lpart,
                        unsigned short* __restrict__ Pws, int bbase)
{
    __shared__ __align__(16) unsigned char smem[36864];
    unsigned short* KtP   = (unsigned short*)smem;
    float*          k8tP  = (float*)(smem + 9216);
    unsigned short* PtP   = (unsigned short*)(smem + 9472);
    float*          mjsP  = (float*)(smem + 23808);
    float*          iljsP = (float*)(smem + 24320);
    unsigned short* QtP   = (unsigned short*)smem;

    const int tid  = threadIdx.x;
    const int w    = tid >> 6;
    const int lane = tid & 63;
    const int g    = lane >> 4;
    const int lr   = lane & 15;

    const int bb = blockIdx.y;
    const int b  = bbase + bb;
    const int jt = blockIdx.x >> 4, kc = blockIdx.x & 15;
    const int jbase = jt * 128;

#pragma unroll
    for (int it = 0; it < 8; ++it) {
        int idx = tid + 512 * it;
        int j = idx & 127, cp = idx >> 7;
        int jg = jbase + j;
        float q0 = 0.f, q1 = 0.f;
        if (jg < HWDIM) {
            const float* qp = qk + ((size_t)b * CKDIM + 2 * cp) * HWDIM + jg;
            q0 = qp[0]; q1 = qp[HWDIM];
        }
        unsigned wh = cvtpk(q0, q1);
        float r0 = q0 - __uint_as_float(wh << 16);
        float r1 = q1 - __uint_as_float(wh & 0xFFFF0000u);
        *(unsigned*)&QtP[(0 * 128 + j) * 72 + 2 * cp] = wh;
        *(unsigned*)&QtP[(1 * 128 + j) * 72 + 2 * cp] = cvtpk(r0, r1);
    }
    __syncthreads();
    bf16x8 bqh[2], bql[2];
#pragma unroll
    for (int s = 0; s < 2; ++s) {
        bqh[s] = *(const bf16x8*)&QtP[(0 * 128 + w * 16 + lr) * 72 + 32 * s + 8 * g];
        bql[s] = *(const bf16x8*)&QtP[(1 * 128 + w * 16 + lr) * 72 + 32 * s + 8 * g];
    }
    __syncthreads();

    const int s0 = (NSTEP * kc) / PCH, s1 = (NSTEP * (kc + 1)) / PCH;

    if (tid < 128) {
        int jg = jbase + tid;
        float m = 0.f, l = 0.f;
        if (jg < HWDIM) {
            m = -1e30f;
#pragma unroll
            for (int c = 0; c < NCHS; ++c) {
                float mc = mpart[(b * NCHS + c) * HWDIM + jg];
                float lc = lpart[(b * NCHS + c) * HWDIM + jg];
                float mn = fmaxf(m, mc);
                l = l * fexp2(m - mn) + lc * fexp2(mc - mn);
                m = mn;
            }
        }
        mjsP[tid]  = m;
        iljsP[tid] = (l > 0.f) ? 1.f / l : 0.f;
    }
    {
        int tt = tid >> 4, cq = tid & 15;
        uint2 k16 = *(const uint2*)(kbt + ((size_t)b * THW + s0 * 32 + tt) * CKDIM + 4 * cq);
        *(uint2*)&KtP[tt * 72 + 4 * cq] = k16;
        if (tid < 32) k8tP[tid] = k8l[b * THW + s0 * 32 + tid];
    }
    __syncthreads();

    const float mv_j = mjsP[w * 16 + lr], il_j = iljsP[w * 16 + lr];
    f32x4 zz = {0.f, 0.f, 0.f, 0.f};

    int cur = 0;
    for (int st = s0; st < s1; ++st) {
        const int t0 = st * 32;
        const bool nxt = (st + 1 < s1);
        uint2 k16;
        float k8next = 0.f;
        const int tt = tid >> 4, cq = tid & 15;
        if (nxt) {
            k16 = *(const uint2*)(kbt + ((size_t)b * THW + (st + 1) * 32 + tt) * CKDIM + 4 * cq);
            if (tid < 32) k8next = k8l[b * THW + (st + 1) * 32 + tid];
        }
        bf16x8 ak0[2], ak1[2];
#pragma unroll
        for (int s = 0; s < 2; ++s) {
            ak0[s] = *(const bf16x8*)&KtP[(cur * 32 + lr) * 72 + 32 * s + 8 * g];
            ak1[s] = *(const bf16x8*)&KtP[(cur * 32 + 16 + lr) * 72 + 32 * s + 8 * g];
        }
        f32x4 k80 = *(const f32x4*)&k8tP[cur * 32 + 4 * g];
        f32x4 k81 = *(const f32x4*)&k8tP[cur * 32 + 16 + 4 * g];
        f32x4 ab0 = zz, ab1 = zz;
#pragma unroll
        for (int s = 0; s < 2; ++s) {
            ab0 = __builtin_amdgcn_mfma_f32_16x16x32_bf16(ak0[s], bqh[s], ab0, 0, 0, 0);
            ab0 = __builtin_amdgcn_mfma_f32_16x16x32_bf16(ak0[s], bql[s], ab0, 0, 0, 0);
            ab1 = __builtin_amdgcn_mfma_f32_16x16x32_bf16(ak1[s], bqh[s], ab1, 0, 0, 0);
            ab1 = __builtin_amdgcn_mfma_f32_16x16x32_bf16(ak1[s], bql[s], ab1, 0, 0, 0);
        }
        if (nxt) {
            *(uint2*)&KtP[((cur ^ 1) * 32 + tt) * 72 + 4 * cq] = k16;
            if (tid < 32) k8tP[(cur ^ 1) * 32 + tid] = k8next;
        }
        float p0[4], p1[4];
#pragma unroll
        for (int r = 0; r < 4; ++r) {
            p0[r] = fexp2(fmaf(ab0[r], S2F, -k80[r]) - mv_j) * il_j;
            p1[r] = fexp2(fmaf(ab1[r], S2F, -k81[r]) - mv_j) * il_j;
        }
        __syncthreads();
        {
            int jl = w * 16 + lr;
            *(uint2*)&PtP[jl * 56 + 4 * g]      = make_uint2(cvtpk(p0[0], p0[1]), cvtpk(p0[2], p0[3]));
            *(uint2*)&PtP[jl * 56 + 16 + 4 * g] = make_uint2(cvtpk(p1[0], p1[1]), cvtpk(p1[2], p1[3]));
        }
        __syncthreads();
        {
            int jr = tid >> 2, qq = tid & 3;
            int jg = jbase + jr;
            if (jg < HWDIM)
                *(uint4*)(Pws + ((size_t)bb * HWDIM + jg) * THWP + t0 + qq * 8) =
                    *(const uint4*)&PtP[jr * 56 + qq * 8];
        }
        cur ^= 1;
    }
}

#ifdef HAVE_GLL
// ---------------- GEMM v6: 8-phase (m201-template) 256x256, BK=64 ----------------
// 512 thr = 8 waves (2M x 4N), per-wave 128x64 (acc[8][4]); 2-dbuf LDS 128 KB;
// per K-tile: 4 phases {12 ds_read ; stage 1 half-tile ; bar ; lgkm0 ; setprio ; 16 MFMA ; vmcnt(4) ; bar}.
// Counted vmcnt never drains to 0 in the main loop (T4); XCD-bijective grid.
#define W4 asm volatile("s_waitcnt vmcnt(4)" ::: "memory")
#define W2 asm volatile("s_waitcnt vmcnt(2)" ::: "memory")
#define W0 asm volatile("s_waitcnt vmcnt(0)" ::: "memory")
#define NOWAIT ((void)0)

#define STAGE_A(H) { size_t o = ((size_t)((H)*128)) * THWP + (size_t)ktn * 64; \
    gload16(sA + o, &Av[cn][(H)*8192 + w*512]); \
    gload16(sA + o + (size_t)64 * THWP, &Av[cn][(H)*8192 + 4096 + w*512]); }
#define STAGE_B(H) { \
    gload16(sB[H][0] + (size_t)ktn * 64, &Bv[cn][(H)*8192 + w*512]); \
    gload16(sB[H][1] + (size_t)ktn * 64, &Bv[cn][(H)*8192 + 4096 + w*512]); }

#define PHASE(QM, QN, STAGE_STMT, WAIT_STMT) { \
    bf16x8 av_[4][2], bp_[2][2]; \
    _Pragma("unroll") for (int mf = 0; mf < 4; ++mf) \
    _Pragma("unroll") for (int ksb = 0; ksb < 2; ++ksb) { \
        int ra = wm*128 + ((QM)*4 + mf)*16 + lr; \
        av_[mf][ksb] = *(const bf16x8*)&Av[bc][ra*64 + (((ksb*4 + g) ^ (ra & 7)) << 3)]; } \
    _Pragma("unroll") for (int nf = 0; nf < 2; ++nf) \
    _Pragma("unroll") for (int ksb = 0; ksb < 2; ++ksb) { \
        int rb = wn*64 + ((QN)*2 + nf)*16 + lr; \
        bp_[nf][ksb] = *(const bf16x8*)&Bv[bc][rb*64 + (((ksb*4 + g) ^ (rb & 7)) << 3)]; } \
    STAGE_STMT; \
    __builtin_amdgcn_s_barrier(); \
    asm volatile("s_waitcnt lgkmcnt(0)" ::: "memory"); \
    __builtin_amdgcn_sched_barrier(0); \
    __builtin_amdgcn_s_setprio(1); \
    _Pragma("unroll") for (int ksb = 0; ksb < 2; ++ksb) \
    _Pragma("unroll") for (int mf = 0; mf < 4; ++mf) \
    _Pragma("unroll") for (int nf = 0; nf < 2; ++nf) \
        acc[(QM)*4 + mf][(QN)*2 + nf] = __builtin_amdgcn_mfma_f32_16x16x32_bf16( \
            av_[mf][ksb], bp_[nf][ksb], acc[(QM)*4 + mf][(QN)*2 + nf], 0, 0, 0); \
    __builtin_amdgcn_s_setprio(0); \
    __builtin_amdgcn_sched_barrier(0); \
    WAIT_STMT; \
    __builtin_amdgcn_s_barrier(); \
    __builtin_amdgcn_sched_barrier(0); }

__global__ __launch_bounds__(512, 2)
void stcn_gemm6_kernel(const unsigned short* __restrict__ mvb,
                       const unsigned short* __restrict__ Pws,
                       const int* __restrict__ bmap, float* __restrict__ out)
{
    __shared__ __align__(16) unsigned short Av[2][256 * 64];   // 64 KB
    __shared__ __align__(16) unsigned short Bv[2][256 * 64];   // 64 KB

    const int wg  = blockIdx.x;               // 448
    const int vid = (wg & 7) * 56 + (wg >> 3);
    const int n   = vid / 56;
    int rr = vid % 56;
    const int cm  = rr / 28; rr %= 28;
    const int ks  = rr / 7;
    const int jn  = rr % 7;
    const int b = bmap[n];
    const int jbase = jn * 256, cbase = cm * 256;

    const int tid = threadIdx.x;              // 512
    const int w = tid >> 6, lane = tid & 63, g = lane >> 4, lr = lane & 15;
    const int wm = w >> 2, wn = w & 3;        // 2(M) x 4(N)

    const int kt0 = ks * KTCH;

    // staging geometry: chunk ch in [0,1024): row = ch>>3, slot = ch&7;
    // swizzled source t-offset uses (row&7) — identical for ch and ch+512 (row+64).
    const int tsw = (((tid & 7) ^ ((tid >> 3) & 7)) << 3);
    const unsigned short* sA = mvb + ((size_t)n * CVAL + cbase + (tid >> 3)) * THWP + tsw;
    const unsigned short* sB[2][2];
#pragma unroll
    for (int h = 0; h < 2; ++h)
#pragma unroll
        for (int k = 0; k < 2; ++k) {
            int jr = jbase + h * 128 + k * 64 + (tid >> 3);
            if (jr >= HWDIM) jr = HWDIM - 1;          // dup row; epilogue discards
            sB[h][k] = Pws + ((size_t)b * HWDIM + jr) * THWP + tsw;
        }

    f32x4 zz = {0.f, 0.f, 0.f, 0.f};
    f32x4 acc[8][4];
#pragma unroll
    for (int i = 0; i < 8; ++i)
#pragma unroll
        for (int j = 0; j < 4; ++j) acc[i][j] = zz;

    // prologue: stage tile kt0 (A0,B0,A1,B1) into buf 0
    {
        int cn = 0, ktn = kt0;
        STAGE_A(0); STAGE_B(0); STAGE_A(1); STAGE_B(1);
    }
    W4;                                        // A0,B0 landed
    __builtin_amdgcn_s_barrier();
    __builtin_amdgcn_sched_barrier(0);

    for (int i = 0; i < KTCH; ++i) {
        const int bc = i & 1, cn = bc ^ 1;
        const int ktn = kt0 + i + 1;
        if (i + 1 < KTCH) {
            PHASE(0, 0, STAGE_A(0), W4);
            PHASE(1, 0, STAGE_B(0), W4);
            PHASE(0, 1, STAGE_A(1), NOWAIT);
            PHASE(1, 1, STAGE_B(1), W4);
        } else {
            PHASE(0, 0, NOWAIT, W2);
            PHASE(1, 0, NOWAIT, W0);
            PHASE(0, 1, NOWAIT, NOWAIT);
            PHASE(1, 1, NOWAIT, NOWAIT);
        }
    }

#pragma unroll
    for (int mf = 0; mf < 8; ++mf)
#pragma unroll
        for (int nf = 0; nf < 4; ++nf) {
            int jg = jbase + wn * 64 + nf * 16 + lr;
            if (jg < HWDIM) {
                int c = cbase + wm * 128 + mf * 16 + 4 * g;
                float* op = out + ((size_t)n * CVAL + c) * HWDIM + jg;
#pragma unroll
                for (int r4 = 0; r4 < 4; ++r4)
                    atomicAdd(op + (size_t)r4 * HWDIM, acc[mf][nf][r4]);
            }
        }
}
#endif  // HAVE_GLL

// ---------------- GEMM v3 (128x128, padded strides) — fallback ----------------
__global__ __launch_bounds__(256, 4)
void stcn_gemm3_kernel(const unsigned short* __restrict__ mvb,
                       const unsigned short* __restrict__ Pws,
                       const int* __restrict__ bmap, float* __restrict__ out, int phase)
{
    __shared__ __align__(16) unsigned short Av[2][128 * 32];
    __shared__ __align__(16) unsigned short Bv[2][128 * 32];

    const int n = blockIdx.y;
    const int b = bmap[n];
    if ((b >> 1) != phase) return;
    const int bslot = b & 1;

    const int x = blockIdx.x;
    const int ks = x & 1;
    const int rest = x >> 1;
    const int jn = rest % NJT;
    const int cm = rest / NJT;
    const int jbase = jn * 128, cbase = cm * 128;

    const int tid = threadIdx.x;
    const int w = tid >> 6, lane = tid & 63, g = lane >> 4, lr = lane & 15;
    const int wc = w >> 1, wj = w & 1;

    const int srow = tid >> 2;
    const int tsw  = (((tid & 3) ^ ((tid >> 3) & 3)) << 3);
    const int gs8  = ((g ^ ((lr >> 1) & 3)) << 3);

    const int s0 = (NSTEP * ks) / 2, s1 = (NSTEP * (ks + 1)) / 2;

    const unsigned short* abase = mvb + ((size_t)n * CVAL + cbase) * THWP;
    const unsigned short* bbase = Pws + (size_t)bslot * HWDIM * THWP;
    int jr0 = jbase + srow;       if (jr0 >= HWDIM) jr0 = 0;
    int jr1 = jbase + 64 + srow;  if (jr1 >= HWDIM) jr1 = 0;
    const unsigned short* ga0 = abase + (size_t)(srow) * THWP + tsw;
    const unsigned short* ga1 = abase + (size_t)(64 + srow) * THWP + tsw;
    const unsigned short* gb0 = bbase + (size_t)jr0 * THWP + tsw;
    const unsigned short* gb1 = bbase + (size_t)jr1 * THWP + tsw;

    f32x4 zz = {0.f, 0.f, 0.f, 0.f};
    f32x4 acc[4][4];
#pragma unroll
    for (int i = 0; i < 4; ++i)
#pragma unroll
        for (int j = 0; j < 4; ++j) acc[i][j] = zz;

#ifdef HAVE_GLL
    auto stage = [&](int buf, int st) {
        const int t0 = st * 32;
        gload16(ga0 + t0, &Av[buf][0    + w * 512]);
        gload16(ga1 + t0, &Av[buf][2048 + w * 512]);
        gload16(gb0 + t0, &Bv[buf][0    + w * 512]);
        gload16(gb1 + t0, &Bv[buf][2048 + w * 512]);
    };
    stage(0, s0);
#else
    {
        const int t0 = s0 * 32;
        *(uint4*)&Av[0][tid * 8]        = *(const uint4*)(ga0 + t0);
        *(uint4*)&Av[0][2048 + tid * 8] = *(const uint4*)(ga1 + t0);
        *(uint4*)&Bv[0][tid * 8]        = *(const uint4*)(gb0 + t0);
        *(uint4*)&Bv[0][2048 + tid * 8] = *(const uint4*)(gb1 + t0);
    }
#endif
    __syncthreads();

    int cur = 0;
    for (int st = s0; st < s1; ++st) {
        const bool nxt = (st + 1 < s1);
#ifdef HAVE_GLL
        if (nxt) stage(cur ^ 1, st + 1);
#else
        uint4 ra0, ra1, rb0, rb1;
        if (nxt) {
            const int t0 = (st + 1) * 32;
            ra0 = *(const uint4*)(ga0 + t0);
            ra1 = *(const uint4*)(ga1 + t0);
            rb0 = *(const uint4*)(gb0 + t0);
            rb1 = *(const uint4*)(gb1 + t0);
        }
#endif
        bf16x8 av[4], bp[4];
#pragma unroll
        for (int cf = 0; cf < 4; ++cf)
            av[cf] = *(const bf16x8*)&Av[cur][(wc * 64 + cf * 16 + lr) * 32 + gs8];
#pragma unroll
        for (int jf = 0; jf < 4; ++jf)
            bp[jf] = *(const bf16x8*)&Bv[cur][(wj * 64 + jf * 16 + lr) * 32 + gs8];
#pragma unroll
        for (int cf = 0; cf < 4; ++cf)
#pragma unroll
            for (int jf = 0; jf < 4; ++jf)
                acc[cf][jf] = __builtin_amdgcn_mfma_f32_16x16x32_bf16(av[cf], bp[jf], acc[cf][jf], 0, 0, 0);
#ifndef HAVE_GLL
        if (nxt) {
            *(uint4*)&Av[cur ^ 1][tid * 8]        = ra0;
            *(uint4*)&Av[cur ^ 1][2048 + tid * 8] = ra1;
            *(uint4*)&Bv[cur ^ 1][tid * 8]        = rb0;
            *(uint4*)&Bv[cur ^ 1][2048 + tid * 8] = rb1;
        }
#endif
        __syncthreads();
        cur ^= 1;
    }

#pragma unroll
    for (int cf = 0; cf < 4; ++cf)
#pragma unroll
        for (int jf = 0; jf < 4; ++jf) {
            int jg = jbase + wj * 64 + jf * 16 + lr;
            if (jg < HWDIM) {
                int c = cbase + wc * 64 + cf * 16 + 4 * g;
                float* op = out + ((size_t)n * CVAL + c) * HWDIM + jg;
#pragma unroll
                for (int r4 = 0; r4 < 4; ++r4)
                    atomicAdd(op + (size_t)r4 * HWDIM, acc[cf][jf][r4]);
            }
        }
}

extern "C" void kernel_launch(void* const* d_in, const int* in_sizes, int n_in,
                              void* d_out, int out_size, void* d_ws, size_t ws_size,
                              hipStream_t stream) {
    (void)in_sizes; (void)n_in;
    const float* mk   = (const float*)d_in[0];
    const float* mv   = (const float*)d_in[1];
    const float* qkp  = (const float*)d_in[2];
    const int*   bmap = (const int*)d_in[3];
    float* out = (float*)d_out;

    float* k8l   = (float*)d_ws;
    float* mpart = k8l + NB * THW;
    float* lpart = mpart + NB * NCHS * HWDIM;
    unsigned short* mvb = (unsigned short*)(lpart + NB * NCHS * HWDIM);
    unsigned short* kbt = mvb + (size_t)NOBJ * CVAL * THWP;
    unsigned short* Pws = kbt + (size_t)NB * THW * CKDIM;

    size_t base_bytes = (size_t)(NB * THW + 2 * NB * NCHS * HWDIM) * 4;
    size_t need_vb  = base_bytes + (size_t)NOBJ * CVAL * THWP * 2;
    size_t need_kbt = need_vb + (size_t)NB * THW * CKDIM * 2;
    size_t need_P2  = need_kbt + (size_t)2 * HWDIM * THWP * 2;
    size_t need_P4  = need_kbt + (size_t)4 * HWDIM * THWP * 2;
    bool use_vb16 = (ws_size >= need_vb);
    bool use_kbt  = (ws_size >= need_kbt);
    bool use_P2   = (ws_size >= need_P2);
    bool use_P4   = (ws_size >= need_P4);

    hipMemsetAsync(d_out, 0, (size_t)out_size * sizeof(float), stream);
    if (use_kbt)
        stcn_ktr_kernel<<<dim3((THW + 63) / 64, NB), 512, 0, stream>>>(mk, kbt, k8l);
    else
        stcn_ksq_kernel<<<dim3((THW + 255) / 256, NB), 256, 0, stream>>>(mk, k8l);
    if (use_vb16) {
        size_t nthreads = (size_t)NOBJ * CVAL * THW / 8;
        stcn_vcvt_kernel<<<(unsigned)((nthreads + 255) / 256), 256, 0, stream>>>(mv, mvb);
        int nPr = use_P4 ? 4 * HWDIM : (use_P2 ? 2 * HWDIM : 0);
        int nz = (NOBJ * CVAL + nPr) * 12;
        stcn_pad0_kernel<<<(nz + 255) / 256, 256, 0, stream>>>(mvb, Pws, nPr);
    }

    if (use_kbt)
        stcn_aff_kernel<0, false, true><<<dim3(NJT * NCHS, NB), 512, 0, stream>>>(
            mk, kbt, qkp, k8l, mpart, lpart, nullptr, nullptr, nullptr, nullptr);
    else
        stcn_aff_kernel<0, false, false><<<dim3(NJT * NCHS, NB), 512, 0, stream>>>(
            mk, nullptr, qkp, k8l, mpart, lpart, nullptr, nullptr, nullptr, nullptr);

#ifdef HAVE_GLL
    if (use_P4 && use_kbt) {
        stcn_pwrite_kernel<<<dim3(NJT * PCH, NB), 512, 0, stream>>>(
            kbt, qkp, k8l, mpart, lpart, Pws, 0);
        stcn_gemm6_kernel<<<dim3(448), 512, 0, stream>>>(mvb, Pws, bmap, out);
    } else
#endif
    if (use_P2 && use_kbt) {
        for (int p = 0; p < 2; ++p) {
            stcn_pwrite_kernel<<<dim3(NJT * PCH, 2), 512, 0, stream>>>(
                kbt, qkp, k8l, mpart, lpart, Pws, 2 * p);
            stcn_gemm3_kernel<<<dim3(104, NOBJ), 256, 0, stream>>>(
                mvb, Pws, bmap, out, p);
        }
    } else {
        dim3 g1(NJT * NCHP * 2, NOBJ);
        if (use_vb16 && use_kbt)
            stcn_aff_kernel<1, true, true><<<g1, 512, 0, stream>>>(
                mk, kbt, qkp, k8l, mpart, lpart, nullptr, mvb, bmap, out);
        else if (use_vb16)
            stcn_aff_kernel<1, true, false><<<g1, 512, 0, stream>>>(
                mk, nullptr, qkp, k8l, mpart, lpart, nullptr, mvb, bmap, out);
        else
            stcn_aff_kernel<1, false, false><<<g1, 512, 0, stream>>>(
                mk, nullptr, qkp, k8l, mpart, lpart, mv, nullptr, bmap, out);
    }
}

// Round 12
// 535.507 us; speedup vs baseline: 1.1017x; 1.1017x over previous
//
#include <hip/hip_runtime.h>
#include <hip/hip_bf16.h>

// STCN read_memory: affinity softmax over THW + value readout.
// Single-S-pass design: P~ = exp2(L - Mbound(j)), l~(j) = sum_t exp2(L - Mbound),
// out = (sum P~ V) / l~.  Mbound = |q|^2/8*log2e >= L exactly (2aq - a^2 = q^2 - |q-a|^2).
#define CKDIM 64
#define THW   12960     // 8*30*54
#define HWDIM 1620      // 30*54
#define NOBJ  8
#define CVAL  512
#define NB    4
#define NSTEP 405       // THW / 32
#define NJT   13        // ceil(1620/128)
#define PCH   16        // P-write K-chunks
#define S2F   0.3606737602222409f   // 0.25 * log2(e)

#if defined(__has_builtin)
#if __has_builtin(__builtin_amdgcn_global_load_lds)
#define HAVE_GLL 1
#endif
#endif

using bf16x8 = __attribute__((ext_vector_type(8))) short;
using f32x4  = __attribute__((ext_vector_type(4))) float;

__device__ __forceinline__ unsigned cvtpk(float lo, float hi) {
    unsigned r;
    asm("v_cvt_pk_bf16_f32 %0, %1, %2" : "=v"(r) : "v"(lo), "v"(hi));
    return r;
}
__device__ __forceinline__ unsigned short bf_rne(float x) {
    unsigned u = __float_as_uint(x);
    u += 0x7FFFu + ((u >> 16) & 1u);
    return (unsigned short)(u >> 16);
}
__device__ __forceinline__ float fexp2(float x) {
#if __has_builtin(__builtin_amdgcn_exp2f)
    return __builtin_amdgcn_exp2f(x);
#else
    return __expf(x * 0.69314718055994531f);
#endif
}
#ifdef HAVE_GLL
__device__ __forceinline__ void gload16(const void* g, void* l) {
    __builtin_amdgcn_global_load_lds(
        (const __attribute__((address_space(1))) unsigned int*)g,
        (__attribute__((address_space(3))) unsigned int*)l, 16, 0, 0);
}
#endif

// K [b][c][t] f32 -> kbt [b][t][c] bf16 (RNE), fused k8l = a^2/8*log2e
__global__ __launch_bounds__(512)
void stcn_ktr_kernel(const float* __restrict__ mk, unsigned short* __restrict__ kbt,
                     float* __restrict__ k8l) {
    __shared__ unsigned short L[64][72];
    __shared__ float S[64][8];
    const int tid = threadIdx.x, b = blockIdx.y, t0 = blockIdx.x * 64;
    const int tt = tid & 63;
    float a2 = 0.f;
#pragma unroll
    for (int it = 0; it < 8; ++it) {
        int idx = tid + 512 * it;
        int c = idx >> 6;
        int t = t0 + tt;
        float v = (t < THW) ? mk[((size_t)b * CKDIM + c) * THW + t] : 0.f;
        L[tt][c] = bf_rne(v);
        a2 = fmaf(v, v, a2);
    }
    S[tt][tid >> 6] = a2;
    __syncthreads();
    if (tid < 64) {
        float s = 0.f;
#pragma unroll
        for (int q = 0; q < 8; ++q) s += S[tid][q];
        int t = t0 + tid;
        if (t < THW) k8l[b * THW + t] = s * (0.125f * 1.44269504088896341f);
    }
    {
        int tr = tid >> 3, cq = tid & 7;
        int t = t0 + tr;
        if (t < THW) {
            uint4 o = *(const uint4*)&L[tr][8 * cq];
            *(uint4*)(kbt + ((size_t)b * THW + t) * CKDIM + 8 * cq) = o;
        }
    }
}

// V f32 -> bf16 (RNE)
__global__ void stcn_vcvt_kernel(const float* __restrict__ mv, unsigned short* __restrict__ mvb) {
    size_t i = ((size_t)blockIdx.x * 256 + threadIdx.x) * 8;
    if (i >= (size_t)NOBJ * CVAL * THW) return;
    float4 v0 = *(const float4*)(mv + i);
    float4 v1 = *(const float4*)(mv + i + 4);
    uint4 o;
    o.x = cvtpk(v0.x, v0.y); o.y = cvtpk(v0.z, v0.w);
    o.z = cvtpk(v1.x, v1.y); o.w = cvtpk(v1.z, v1.w);
    *(uint4*)(mvb + i) = o;
}

// Mbound[b][j] = (sum_c q^2)/8 * log2e  (exact upper bound on log2-logits)
__global__ void stcn_qbound_kernel(const float* __restrict__ qk, float* __restrict__ mbnd) {
    int j = blockIdx.x * 256 + threadIdx.x;
    if (j >= HWDIM) return;
    int b = blockIdx.y;
    const float* p = qk + (size_t)b * CKDIM * HWDIM + j;
    float s = 0.f;
#pragma unroll
    for (int c = 0; c < CKDIM; ++c) { float v = p[(size_t)c * HWDIM]; s = fmaf(v, v, s); }
    mbnd[b * HWDIM + j] = s * (0.125f * 1.44269504088896341f);
}

// ---------------- single-pass P-write: P~ (bf16) -> Pws[slot][j][THW], l~ atomics ----------------
__global__ __launch_bounds__(512)
void stcn_pwrite_kernel(const unsigned short* __restrict__ kbt,
                        const float* __restrict__ qk, const float* __restrict__ k8l,
                        const float* __restrict__ mbnd, float* __restrict__ lws,
                        unsigned short* __restrict__ Pws, int bbase)
{
    // steady: Kt[2][32][72] @0 (9216) | k8t[2][32] @9216 (256) | Pt[128][56] @9472 (14336)
    // transient: Qt[2][128][72] @0..36864 (dead after prologue)
    __shared__ __align__(16) unsigned char smem[36864];
    unsigned short* KtP  = (unsigned short*)smem;
    float*          k8tP = (float*)(smem + 9216);
    unsigned short* PtP  = (unsigned short*)(smem + 9472);
    unsigned short* QtP  = (unsigned short*)smem;

    const int tid  = threadIdx.x;
    const int w    = tid >> 6;
    const int lane = tid & 63;
    const int g    = lane >> 4;
    const int lr   = lane & 15;

    const int bb = blockIdx.y;            // Pws slot
    const int b  = bbase + bb;
    const int jt = blockIdx.x >> 4, kc = blockIdx.x & 15;
    const int jbase = jt * 128;

    // ---- Q prologue: hi/lo bf16 split (f32-accurate logits) ----
#pragma unroll
    for (int it = 0; it < 8; ++it) {
        int idx = tid + 512 * it;
        int j = idx & 127, cp = idx >> 7;
        int jg = jbase + j;
        float q0 = 0.f, q1 = 0.f;
        if (jg < HWDIM) {
            const float* qp = qk + ((size_t)b * CKDIM + 2 * cp) * HWDIM + jg;
            q0 = qp[0]; q1 = qp[HWDIM];
        }
        unsigned wh = cvtpk(q0, q1);
        float r0 = q0 - __uint_as_float(wh << 16);
        float r1 = q1 - __uint_as_float(wh & 0xFFFF0000u);
        *(unsigned*)&QtP[(0 * 128 + j) * 72 + 2 * cp] = wh;
        *(unsigned*)&QtP[(1 * 128 + j) * 72 + 2 * cp] = cvtpk(r0, r1);
    }
    __syncthreads();
    bf16x8 bqh[2], bql[2];
#pragma unroll
    for (int s = 0; s < 2; ++s) {
        bqh[s] = *(const bf16x8*)&QtP[(0 * 128 + w * 16 + lr) * 72 + 32 * s + 8 * g];
        bql[s] = *(const bf16x8*)&QtP[(1 * 128 + w * 16 + lr) * 72 + 32 * s + 8 * g];
    }
    __syncthreads();   // Qt dead

    const int s0 = (NSTEP * kc) / PCH, s1 = (NSTEP * (kc + 1)) / PCH;

    const int jgq = jbase + w * 16 + lr;                       // this thread's column
    const float mv_j = (jgq < HWDIM) ? mbnd[b * HWDIM + jgq] : 0.f;
    float lsum = 0.f;

    {   // stage first K tile into buf 0
        int tt = tid >> 4, cq = tid & 15;
        uint2 k16 = *(const uint2*)(kbt + ((size_t)b * THW + s0 * 32 + tt) * CKDIM + 4 * cq);
        *(uint2*)&KtP[tt * 72 + 4 * cq] = k16;
        if (tid < 32) k8tP[tid] = k8l[b * THW + s0 * 32 + tid];
    }
    __syncthreads();

    f32x4 zz = {0.f, 0.f, 0.f, 0.f};
    int cur = 0;
    for (int st = s0; st < s1; ++st) {
        const int t0 = st * 32;
        const bool nxt = (st + 1 < s1);
        uint2 k16;
        float k8next = 0.f;
        const int tt = tid >> 4, cq = tid & 15;
        if (nxt) {
            k16 = *(const uint2*)(kbt + ((size_t)b * THW + (st + 1) * 32 + tt) * CKDIM + 4 * cq);
            if (tid < 32) k8next = k8l[b * THW + (st + 1) * 32 + tid];
        }
        bf16x8 ak0[2], ak1[2];
#pragma unroll
        for (int s = 0; s < 2; ++s) {
            ak0[s] = *(const bf16x8*)&KtP[(cur * 32 + lr) * 72 + 32 * s + 8 * g];
            ak1[s] = *(const bf16x8*)&KtP[(cur * 32 + 16 + lr) * 72 + 32 * s + 8 * g];
        }
        f32x4 k80 = *(const f32x4*)&k8tP[cur * 32 + 4 * g];
        f32x4 k81 = *(const f32x4*)&k8tP[cur * 32 + 16 + 4 * g];
        f32x4 ab0 = zz, ab1 = zz;
#pragma unroll
        for (int s = 0; s < 2; ++s) {
            ab0 = __builtin_amdgcn_mfma_f32_16x16x32_bf16(ak0[s], bqh[s], ab0, 0, 0, 0);
            ab0 = __builtin_amdgcn_mfma_f32_16x16x32_bf16(ak0[s], bql[s], ab0, 0, 0, 0);
            ab1 = __builtin_amdgcn_mfma_f32_16x16x32_bf16(ak1[s], bqh[s], ab1, 0, 0, 0);
            ab1 = __builtin_amdgcn_mfma_f32_16x16x32_bf16(ak1[s], bql[s], ab1, 0, 0, 0);
        }
        if (nxt) {
            *(uint2*)&KtP[((cur ^ 1) * 32 + tt) * 72 + 4 * cq] = k16;
            if (tid < 32) k8tP[(cur ^ 1) * 32 + tid] = k8next;
        }
        float p0[4], p1[4];
#pragma unroll
        for (int r = 0; r < 4; ++r) {
            p0[r] = fexp2(fmaf(ab0[r], S2F, -k80[r]) - mv_j);   // <= ~1 by construction
            p1[r] = fexp2(fmaf(ab1[r], S2F, -k81[r]) - mv_j);
        }
        lsum += (p0[0] + p0[1] + p0[2] + p0[3]) + (p1[0] + p1[1] + p1[2] + p1[3]);
        __syncthreads();   // prev Pt consumers done
        {
            int jl = w * 16 + lr;
            *(uint2*)&PtP[jl * 56 + 4 * g]      = make_uint2(cvtpk(p0[0], p0[1]), cvtpk(p0[2], p0[3]));
            *(uint2*)&PtP[jl * 56 + 16 + 4 * g] = make_uint2(cvtpk(p1[0], p1[1]), cvtpk(p1[2], p1[3]));
        }
        __syncthreads();   // Pt ready
        {
            int jr = tid >> 2, qq = tid & 3;
            int jg = jbase + jr;
            if (jg < HWDIM)
                *(uint4*)(Pws + ((size_t)bb * HWDIM + jg) * THW + t0 + qq * 8) =
                    *(const uint4*)&PtP[jr * 56 + qq * 8];
        }
        cur ^= 1;
    }

    // l~ partial: combine the 4 g-groups (lanes lr, lr+16, lr+32, lr+48), one atomic per column
    lsum += __shfl_xor(lsum, 16, 64);
    lsum += __shfl_xor(lsum, 32, 64);
    if (g == 0 && jgq < HWDIM)
        atomicAdd(&lws[b * HWDIM + jgq], lsum);
}

// ---------------- GEMM (R8-proven): out[n][c][j] += (sum_t V P~) / l~(b,j) ----------------
// 128c x 128j tile, 4 waves of 64x64, BK=32, global_load_lds dbuf, slot-XOR swizzle.
// FULLP: 1-D grid 1664 = 8n x 4cm x 13jn x 4ks, XCD-bijective (one n per XCD).
template <bool FULLP>
__global__ __launch_bounds__(256, 4)
void stcn_gemm3_kernel(const unsigned short* __restrict__ mvb,
                       const unsigned short* __restrict__ Pws,
                       const float* __restrict__ lws,
                       const int* __restrict__ bmap, float* __restrict__ out, int phase)
{
    __shared__ __align__(16) unsigned short Av[2][128 * 32];
    __shared__ __align__(16) unsigned short Bv[2][128 * 32];

    int n, cm, jn, ks, ksplit, bslot;
    if constexpr (FULLP) {
        int wg  = blockIdx.x;                      // 1664
        int vid = (wg & 7) * 208 + (wg >> 3);      // bijective: each XCD owns one n
        n = vid / 208;
        int r  = vid % 208;
        cm = r / 52;
        int r2 = r % 52;
        jn = r2 >> 2;
        ks = r2 & 3;
        ksplit = 4;
    } else {
        n = blockIdx.y;
        const int x = blockIdx.x;                  // 2ks x 13jn x 4cm = 104
        ks = x & 1;
        const int rest = x >> 1;
        jn = rest % NJT;
        cm = rest / NJT;
        ksplit = 2;
    }
    const int b = bmap[n];
    if constexpr (FULLP) { bslot = b; }
    else { if ((b >> 1) != phase) return; bslot = b & 1; }

    const int jbase = jn * 128, cbase = cm * 128;

    const int tid = threadIdx.x;          // 256
    const int w = tid >> 6, lane = tid & 63, g = lane >> 4, lr = lane & 15;
    const int wc = w >> 1, wj = w & 1;    // 2x2 wave grid, 64x64 per wave

    const int srow = tid >> 2;
    const int tsw  = (((tid & 3) ^ ((tid >> 3) & 3)) << 3);   // pre-swizzled source t-offset
    const int gs8  = ((g ^ ((lr >> 1) & 3)) << 3);            // read-side swizzle

    const int s0 = (NSTEP * ks) / ksplit, s1 = (NSTEP * (ks + 1)) / ksplit;

    const unsigned short* abase = mvb + ((size_t)n * CVAL + cbase) * THW;
    const unsigned short* bbase = Pws + (size_t)bslot * HWDIM * THW;
    int jr0 = jbase + srow;       if (jr0 >= HWDIM) jr0 = 0;
    int jr1 = jbase + 64 + srow;  if (jr1 >= HWDIM) jr1 = 0;
    const unsigned short* ga0 = abase + (size_t)(srow) * THW + tsw;
    const unsigned short* ga1 = abase + (size_t)(64 + srow) * THW + tsw;
    const unsigned short* gb0 = bbase + (size_t)jr0 * THW + tsw;
    const unsigned short* gb1 = bbase + (size_t)jr1 * THW + tsw;

    f32x4 zz = {0.f, 0.f, 0.f, 0.f};
    f32x4 acc[4][4];
#pragma unroll
    for (int i = 0; i < 4; ++i)
#pragma unroll
        for (int j = 0; j < 4; ++j) acc[i][j] = zz;

#ifdef HAVE_GLL
    auto stage = [&](int buf, int st) {
        const int t0 = st * 32;
        gload16(ga0 + t0, &Av[buf][0    + w * 512]);
        gload16(ga1 + t0, &Av[buf][2048 + w * 512]);
        gload16(gb0 + t0, &Bv[buf][0    + w * 512]);
        gload16(gb1 + t0, &Bv[buf][2048 + w * 512]);
    };
    stage(0, s0);
#else
    {
        const int t0 = s0 * 32;
        *(uint4*)&Av[0][tid * 8]        = *(const uint4*)(ga0 + t0);
        *(uint4*)&Av[0][2048 + tid * 8] = *(const uint4*)(ga1 + t0);
        *(uint4*)&Bv[0][tid * 8]        = *(const uint4*)(gb0 + t0);
        *(uint4*)&Bv[0][2048 + tid * 8] = *(const uint4*)(gb1 + t0);
    }
#endif
    __syncthreads();

    int cur = 0;
    for (int st = s0; st < s1; ++st) {
        const bool nxt = (st + 1 < s1);
#ifdef HAVE_GLL
        if (nxt) stage(cur ^ 1, st + 1);
#else
        uint4 ra0, ra1, rb0, rb1;
        if (nxt) {
            const int t0 = (st + 1) * 32;
            ra0 = *(const uint4*)(ga0 + t0);
            ra1 = *(const uint4*)(ga1 + t0);
            rb0 = *(const uint4*)(gb0 + t0);
            rb1 = *(const uint4*)(gb1 + t0);
        }
#endif
        bf16x8 av[4], bp[4];
#pragma unroll
        for (int cf = 0; cf < 4; ++cf)
            av[cf] = *(const bf16x8*)&Av[cur][(wc * 64 + cf * 16 + lr) * 32 + gs8];
#pragma unroll
        for (int jf = 0; jf < 4; ++jf)
            bp[jf] = *(const bf16x8*)&Bv[cur][(wj * 64 + jf * 16 + lr) * 32 + gs8];
#pragma unroll
        for (int cf = 0; cf < 4; ++cf)
#pragma unroll
            for (int jf = 0; jf < 4; ++jf)
                acc[cf][jf] = __builtin_amdgcn_mfma_f32_16x16x32_bf16(av[cf], bp[jf], acc[cf][jf], 0, 0, 0);
#ifndef HAVE_GLL
        if (nxt) {
            *(uint4*)&Av[cur ^ 1][tid * 8]        = ra0;
            *(uint4*)&Av[cur ^ 1][2048 + tid * 8] = ra1;
            *(uint4*)&Bv[cur ^ 1][tid * 8]        = rb0;
            *(uint4*)&Bv[cur ^ 1][2048 + tid * 8] = rb1;
        }
#endif
        __syncthreads();
        cur ^= 1;
    }

    // epilogue: scale by 1/l~(b, j) then atomic-accumulate
    float il[4];
#pragma unroll
    for (int jf = 0; jf < 4; ++jf) {
        int jg = jbase + wj * 64 + jf * 16 + lr;
        il[jf] = (jg < HWDIM) ? 1.0f / lws[b * HWDIM + jg] : 0.f;
    }
#pragma unroll
    for (int cf = 0; cf < 4; ++cf)
#pragma unroll
        for (int jf = 0; jf < 4; ++jf) {
            int jg = jbase + wj * 64 + jf * 16 + lr;
            if (jg < HWDIM) {
                int c = cbase + wc * 64 + cf * 16 + 4 * g;
                float* op = out + ((size_t)n * CVAL + c) * HWDIM + jg;
#pragma unroll
                for (int r4 = 0; r4 < 4; ++r4)
                    atomicAdd(op + (size_t)r4 * HWDIM, acc[cf][jf][r4] * il[jf]);
            }
        }
}

extern "C" void kernel_launch(void* const* d_in, const int* in_sizes, int n_in,
                              void* d_out, int out_size, void* d_ws, size_t ws_size,
                              hipStream_t stream) {
    (void)in_sizes; (void)n_in;
    const float* mk   = (const float*)d_in[0];   // mem_keys   [4,64,12960]
    const float* mv   = (const float*)d_in[1];   // mem_values [8,512,12960]
    const float* qkp  = (const float*)d_in[2];   // qk         [4,64,1620]
    const int*   bmap = (const int*)d_in[3];     // broadcast_map [8]
    float* out = (float*)d_out;

    // ws layout: k8l | mbnd | lws | mvb | kbt | Pws
    float* k8l  = (float*)d_ws;                           // NB*THW
    float* mbnd = k8l + NB * THW;                         // NB*HWDIM
    float* lws  = mbnd + NB * HWDIM;                      // NB*HWDIM
    unsigned short* mvb = (unsigned short*)(lws + NB * HWDIM);
    unsigned short* kbt = mvb + (size_t)NOBJ * CVAL * THW;
    unsigned short* Pws = kbt + (size_t)NB * THW * CKDIM;

    size_t base = ((size_t)NB * THW + 2 * (size_t)NB * HWDIM) * 4;
    size_t mvbB = (size_t)NOBJ * CVAL * THW * 2;
    size_t kbtB = (size_t)NB * THW * CKDIM * 2;
    size_t need_P4 = base + mvbB + kbtB + (size_t)4 * HWDIM * THW * 2;   // ~281.0 MB
    bool use_P4 = (ws_size >= need_P4);

    hipMemsetAsync(d_out, 0, (size_t)out_size * sizeof(float), stream);
    hipMemsetAsync(lws, 0, (size_t)NB * HWDIM * sizeof(float), stream);

    stcn_ktr_kernel<<<dim3((THW + 63) / 64, NB), 512, 0, stream>>>(mk, kbt, k8l);
    {
        size_t nthreads = (size_t)NOBJ * CVAL * THW / 8;
        stcn_vcvt_kernel<<<(unsigned)((nthreads + 255) / 256), 256, 0, stream>>>(mv, mvb);
    }
    stcn_qbound_kernel<<<dim3((HWDIM + 255) / 256, NB), 256, 0, stream>>>(qkp, mbnd);

    if (use_P4) {
        // one P pass for all 4 batches + one big GEMM
        stcn_pwrite_kernel<<<dim3(NJT * PCH, NB), 512, 0, stream>>>(
            kbt, qkp, k8l, mbnd, lws, Pws, 0);
        stcn_gemm3_kernel<true><<<dim3(1664), 256, 0, stream>>>(
            mvb, Pws, lws, bmap, out, 0);
    } else {
        // phased: P for b in {0,1} then {2,3}; inactive objects early-exit in GEMM
        for (int p = 0; p < 2; ++p) {
            stcn_pwrite_kernel<<<dim3(NJT * PCH, 2), 512, 0, stream>>>(
                kbt, qkp, k8l, mbnd, lws, Pws, 2 * p);
            stcn_gemm3_kernel<false><<<dim3(104, NOBJ), 256, 0, stream>>>(
                mvb, Pws, lws, bmap, out, p);
        }
    }
}